// Round 1
// 262.529 us; speedup vs baseline: 1.0948x; 1.0948x over previous
//
#include <hip/hip_runtime.h>
#include <stdint.h>

typedef __attribute__((ext_vector_type(8))) short s16x8;
typedef __attribute__((ext_vector_type(4))) float f32x4;

__device__ __forceinline__ unsigned short f2bf(float f) {
  unsigned int u = __float_as_uint(f);
  u += 0x7fffu + ((u >> 16) & 1u);
  return (unsigned short)(u >> 16);
}
__device__ __forceinline__ float bf2f(unsigned short h) {
  return __uint_as_float(((unsigned int)h) << 16);
}
__device__ __forceinline__ f32x4 mfma16(s16x8 a, s16x8 b, f32x4 c) {
  return __builtin_amdgcn_mfma_f32_16x16x32_bf16(a, b, c, 0, 0, 0);
}

// ---------------- attention kernel: one block per batch ----------------
// LDS plan (union, 32768 B total -> 5 blocks/CU; was 46080 -> 3 blocks/CU):
//  QK phases: Kh[64][128] @0 (16384 B, XOR-swizzled), Kl[64][128] @16384
//  PV phase : Vt[128][72] @0 (18432 B, one e-half at a time), P[64][72] @18432 (9216 B)
//  epilogue : X[64][128] fp32 @0 (32768 B, XOR-swizzled, one e-half per pass)
__global__ __launch_bounds__(256) void attn_kernel(
    const float* __restrict__ Vg, const float* __restrict__ Kg,
    const float* __restrict__ Qg, float* __restrict__ attn_out,
    unsigned short* __restrict__ xb /* bf16 x = attn+q, may be null */) {
  __shared__ __align__(16) char smem[32768];
  char* KhB = smem;
  char* KlB = smem + 16384;
  unsigned short* VtL = (unsigned short*)smem;
  unsigned short* PL = (unsigned short*)(smem + 18432);

  const int b = blockIdx.x;
  const int tid = threadIdx.x;
  const int lane = tid & 63;
  const int w = tid >> 6;  // wave id: owns S/A rows 16w..16w+15
  const int n = lane & 15;
  const int q = lane >> 4;

  const float* Qb = Qg + (size_t)b * 64 * 256;
  const float* Kb = Kg + (size_t)b * 64 * 256;
  const float* Vb = Vg + (size_t)b * 64 * 256;

  f32x4 accS[4];
#pragma unroll
  for (int c = 0; c < 4; ++c) accS[c] = f32x4{0.f, 0.f, 0.f, 0.f};

  float va[16], vbv[16];  // V half staging registers (prefetch)

  // ---- S = Q K^T, hi/lo bf16 split, two 128-wide e-chunks ----
  for (int ph = 0; ph < 2; ++ph) {
    const int e0 = ph * 128;
    // stage K chunk 64x128 fp32 -> hi/lo bf16 LDS (XOR-swizzled, stride 128)
#pragma unroll
    for (int it = 0; it < 8; ++it) {
      int i = it * 256 + tid;
      int row = i >> 5;
      int c4 = i & 31;
      float4 v = *(const float4*)(Kb + row * 256 + e0 + c4 * 4);
      ushort4 hi, lo;
      hi.x = f2bf(v.x); lo.x = f2bf(v.x - bf2f(hi.x));
      hi.y = f2bf(v.y); lo.y = f2bf(v.y - bf2f(hi.y));
      hi.z = f2bf(v.z); lo.z = f2bf(v.z - bf2f(hi.z));
      hi.w = f2bf(v.w); lo.w = f2bf(v.w - bf2f(hi.w));
      int off = row * 256 + ((c4 * 8) ^ ((row & 7) << 4));
      *(ushort4*)(KhB + off) = hi;
      *(ushort4*)(KlB + off) = lo;
    }
    __syncthreads();
    // preload Q fragments first (so their vmcnt waits don't chain on V loads)
    float4 qf0[4], qf1[4];
#pragma unroll
    for (int kk = 0; kk < 4; ++kk) {
      const float* qsrc = Qb + (16 * w + n) * 256 + e0 + kk * 32 + q * 8;
      qf0[kk] = *(const float4*)qsrc;
      qf1[kk] = *(const float4*)(qsrc + 4);
    }
    if (ph == 1) {
      // prefetch V e-half 0 into registers; latency hides under phase-2 MFMA
#pragma unroll
      for (int i = 0; i < 16; ++i) {
        int j = i * 256 + tid, e = j & 127, tp = j >> 7;
        va[i] = Vb[(2 * tp) * 256 + e];
        vbv[i] = Vb[(2 * tp + 1) * 256 + e];
      }
    }
    __builtin_amdgcn_s_setprio(1);
#pragma unroll
    for (int kk = 0; kk < 4; ++kk) {
      float av[8] = {qf0[kk].x, qf0[kk].y, qf0[kk].z, qf0[kk].w,
                     qf1[kk].x, qf1[kk].y, qf1[kk].z, qf1[kk].w};
      s16x8 qh, ql;
#pragma unroll
      for (int j = 0; j < 8; ++j) {
        unsigned short h = f2bf(av[j]);
        qh[j] = (short)h;
        ql[j] = (short)f2bf(av[j] - bf2f(h));
      }
      const int cb = (kk * 32 + q * 8) * 2;
#pragma unroll
      for (int c = 0; c < 4; ++c) {
        int row = 16 * c + n;
        int off = row * 256 + (cb ^ ((row & 7) << 4));
        s16x8 kh = *(const s16x8*)(KhB + off);
        s16x8 kl = *(const s16x8*)(KlB + off);
        accS[c] = mfma16(qh, kh, accS[c]);
        accS[c] = mfma16(qh, kl, accS[c]);
        accS[c] = mfma16(ql, kh, accS[c]);
      }
    }
    __builtin_amdgcn_s_setprio(0);
    __syncthreads();  // before restaging / Vt overwrite
  }

  // ---- in-register softmax. lane holds S[16w+4q+r][16c+n] in accS[c][r] ----
  const float scale = 0.125f;
  float p[4][4];
#pragma unroll
  for (int r = 0; r < 4; ++r) {
    float m = -1e30f;
#pragma unroll
    for (int c = 0; c < 4; ++c) m = fmaxf(m, accS[c][r]);
#pragma unroll
    for (int mk = 1; mk < 16; mk <<= 1) m = fmaxf(m, __shfl_xor(m, mk, 64));
    float s = 0.f;
#pragma unroll
    for (int c = 0; c < 4; ++c) {
      float e = __expf((accS[c][r] - m) * scale);
      p[c][r] = e;
      s += e;
    }
#pragma unroll
    for (int mk = 1; mk < 16; mk <<= 1) s += __shfl_xor(s, mk, 64);
    float inv = 1.0f / s;
#pragma unroll
    for (int c = 0; c < 4; ++c) p[c][r] *= inv;
  }

  // ---- stage V^T e-half 0 (from prefetched regs) and P (bf16) ----
#pragma unroll
  for (int i = 0; i < 16; ++i) {
    int j = i * 256 + tid, e = j & 127, tp = j >> 7;
    unsigned int pk = (unsigned int)f2bf(va[i]) | ((unsigned int)f2bf(vbv[i]) << 16);
    *(unsigned int*)(VtL + e * 72 + 2 * tp) = pk;
  }
#pragma unroll
  for (int r = 0; r < 4; ++r) {
    int row = 16 * w + 4 * q + r;
#pragma unroll
    for (int c = 0; c < 4; ++c) PL[row * 72 + 16 * c + n] = f2bf(p[c][r]);
  }
  // prefetch V e-half 1 into regs; latency hides under PV half-0
#pragma unroll
  for (int i = 0; i < 16; ++i) {
    int j = i * 256 + tid, e = j & 127, tp = j >> 7;
    va[i] = Vb[(2 * tp) * 256 + 128 + e];
    vbv[i] = Vb[(2 * tp + 1) * 256 + 128 + e];
  }
  __syncthreads();

  // ---- A = P V via MFMA, wave w does rows 16w..16w+15; e-halves of 128 ----
  f32x4 accA[16];
#pragma unroll
  for (int c = 0; c < 16; ++c) accA[c] = f32x4{0.f, 0.f, 0.f, 0.f};

  __builtin_amdgcn_s_setprio(1);
#pragma unroll
  for (int ks = 0; ks < 2; ++ks) {
    const int colb = ks * 32 + q * 8;
    s16x8 af = *(const s16x8*)(PL + (16 * w + n) * 72 + colb);
#pragma unroll
    for (int c = 0; c < 8; ++c) {
      s16x8 bf = *(const s16x8*)(VtL + (16 * c + n) * 72 + colb);
      accA[c] = mfma16(af, bf, accA[c]);
    }
  }
  __builtin_amdgcn_s_setprio(0);
  __syncthreads();
  // stage V^T e-half 1
#pragma unroll
  for (int i = 0; i < 16; ++i) {
    int j = i * 256 + tid, e = j & 127, tp = j >> 7;
    unsigned int pk = (unsigned int)f2bf(va[i]) | ((unsigned int)f2bf(vbv[i]) << 16);
    *(unsigned int*)(VtL + e * 72 + 2 * tp) = pk;
  }
  __syncthreads();
  __builtin_amdgcn_s_setprio(1);
#pragma unroll
  for (int ks = 0; ks < 2; ++ks) {
    const int colb = ks * 32 + q * 8;
    s16x8 af = *(const s16x8*)(PL + (16 * w + n) * 72 + colb);
#pragma unroll
    for (int c = 8; c < 16; ++c) {
      s16x8 bf = *(const s16x8*)(VtL + (16 * (c - 8) + n) * 72 + colb);
      accA[c] = mfma16(af, bf, accA[c]);
    }
  }
  __builtin_amdgcn_s_setprio(0);

  // ---- epilogue ----
  if (xb) {
    // 2-pass fp32 transpose through LDS: exact-precision attention + x = attn+q,
    // all global traffic vectorized/coalesced (float4 Q loads, float4 attn
    // stores, 8-B xb stores).
#pragma unroll
    for (int h = 0; h < 2; ++h) {
      __syncthreads();  // previous LDS users (PV reads / pass-0 reads) done
#pragma unroll
      for (int r = 0; r < 4; ++r) {
        int t = 16 * w + 4 * q + r;
        int sw = (t & 7) << 4;
#pragma unroll
        for (int c8 = 0; c8 < 8; ++c8) {
          int c = h * 8 + c8;
          int el = 16 * c8 + n;  // e - 128*h
          *(float*)(smem + t * 512 + ((el * 4) ^ sw)) = accA[c][r];
        }
      }
      __syncthreads();
#pragma unroll
      for (int i = 0; i < 8; ++i) {
        int f4 = i * 256 + tid;
        int row = f4 >> 5;       // 32 float4 per 128-wide row
        int col4 = f4 & 31;
        int e = h * 128 + col4 * 4;
        float4 av = *(const float4*)(smem + row * 512 + ((col4 * 16) ^ ((row & 7) << 4)));
        float4 qv = *(const float4*)(Qb + row * 256 + e);
        size_t base = ((size_t)b * 64 + row) * 256 + e;
        *(float4*)(attn_out + base) = av;
        ushort4 o;
        o.x = f2bf(av.x + qv.x);
        o.y = f2bf(av.y + qv.y);
        o.z = f2bf(av.z + qv.z);
        o.w = f2bf(av.w + qv.w);
        *(ushort4*)(xb + base) = o;
      }
    }
  } else {
    // fallback: direct strided stores
#pragma unroll
    for (int r = 0; r < 4; ++r) {
      int t = 16 * w + 4 * q + r;
      size_t base = ((size_t)b * 64 + t) * 256;
#pragma unroll
      for (int c = 0; c < 16; ++c) attn_out[base + 16 * c + n] = accA[c][r];
    }
  }
}

// ---------------- W_ff fp32 -> bf16 ----------------
__global__ __launch_bounds__(256) void w2b_kernel(const float* __restrict__ W,
                                                  unsigned short* __restrict__ Wb) {
  int i = blockIdx.x * 256 + threadIdx.x;  // one float4 each, grid covers exactly
  float4 v = ((const float4*)W)[i];
  ushort4 o;
  o.x = f2bf(v.x); o.y = f2bf(v.y); o.z = f2bf(v.z); o.w = f2bf(v.w);
  ((ushort4*)Wb)[i] = o;
}

// ---------------- FF GEMM: out_part = x @ W^T, 64x64 tiles, K-split ----------------
template <bool USE_XB>
__global__ __launch_bounds__(256) void ff_kernel(
    const unsigned short* __restrict__ xb, const float* __restrict__ attn,
    const float* __restrict__ query, const unsigned short* __restrict__ Wb,
    float* __restrict__ part, int kchunk) {
  __shared__ __align__(16) unsigned short As[64 * 72];
  __shared__ __align__(16) unsigned short Bs[64 * 72];
  const int tid = threadIdx.x;
  const int lane = tid & 63, w = tid >> 6, n = lane & 15, q = lane >> 4;
  const int m0 = blockIdx.x * 64;
  const int n0 = blockIdx.y * 64;
  const int k0 = blockIdx.z * kchunk;

  f32x4 acc[4];
#pragma unroll
  for (int c = 0; c < 4; ++c) acc[c] = f32x4{0.f, 0.f, 0.f, 0.f};

  const int srow = tid >> 3;  // 0..31
  const int scol = (tid & 7) * 8;

  for (int kk = 0; kk < kchunk; kk += 64) {
#pragma unroll
    for (int rr = 0; rr < 2; ++rr) {
      int row = rr * 32 + srow;
      size_t ga = (size_t)(m0 + row) * 16384 + k0 + kk + scol;
      if (USE_XB) {
        *(uint4*)(As + row * 72 + scol) = *(const uint4*)(xb + ga);
      } else {
        float4 a0 = *(const float4*)(attn + ga);
        float4 a1 = *(const float4*)(attn + ga + 4);
        float4 q0 = *(const float4*)(query + ga);
        float4 q1 = *(const float4*)(query + ga + 4);
        ushort4 h0, h1;
        h0.x = f2bf(a0.x + q0.x); h0.y = f2bf(a0.y + q0.y);
        h0.z = f2bf(a0.z + q0.z); h0.w = f2bf(a0.w + q0.w);
        h1.x = f2bf(a1.x + q1.x); h1.y = f2bf(a1.y + q1.y);
        h1.z = f2bf(a1.z + q1.z); h1.w = f2bf(a1.w + q1.w);
        *(ushort4*)(As + row * 72 + scol) = h0;
        *(ushort4*)(As + row * 72 + scol + 4) = h1;
      }
      size_t gw = (size_t)(n0 + row) * 16384 + k0 + kk + scol;
      *(uint4*)(Bs + row * 72 + scol) = *(const uint4*)(Wb + gw);
    }
    __syncthreads();
#pragma unroll
    for (int ks = 0; ks < 2; ++ks) {
      const int colb = ks * 32 + q * 8;
      s16x8 af = *(const s16x8*)(As + (16 * w + n) * 72 + colb);
#pragma unroll
      for (int c = 0; c < 4; ++c) {
        s16x8 bf = *(const s16x8*)(Bs + (16 * c + n) * 72 + colb);
        acc[c] = mfma16(af, bf, acc[c]);
      }
    }
    __syncthreads();
  }
#pragma unroll
  for (int r = 0; r < 4; ++r) {
    int m = m0 + 16 * w + 4 * q + r;
#pragma unroll
    for (int c = 0; c < 4; ++c) {
      int nn = n0 + 16 * c + n;
      part[((size_t)blockIdx.z * 2048 + m) * 256 + nn] = acc[c][r];
    }
  }
}

// ---------------- reduce K-split partials + bias + ReLU ----------------
__global__ __launch_bounds__(256) void relu_kernel(const float* __restrict__ part,
                                                   const float* __restrict__ bias,
                                                   float* __restrict__ out, int KS) {
  int idx = blockIdx.x * 256 + threadIdx.x;
  float s = bias[idx & 255];
  for (int ks = 0; ks < KS; ++ks) s += part[(size_t)ks * 2048 * 256 + idx];
  out[idx] = fmaxf(s, 0.f);
}

extern "C" void kernel_launch(void* const* d_in, const int* in_sizes, int n_in,
                              void* d_out, int out_size, void* d_ws, size_t ws_size,
                              hipStream_t stream) {
  const float* value = (const float*)d_in[0];
  const float* key   = (const float*)d_in[1];
  const float* query = (const float*)d_in[2];
  // d_in[3] = mask, unused by the block
  const float* W_ff  = (const float*)d_in[4];
  const float* b_ff  = (const float*)d_in[5];

  float* out  = (float*)d_out;
  float* attn = out + (size_t)2048 * 256;  // outputs: (out, attention) concatenated

  const int KS = 4;
  const size_t wb_bytes   = (size_t)256 * 16384 * 2;      // 8 MB bf16 W
  const size_t part_bytes = (size_t)KS * 2048 * 256 * 4;  // 8 MB fp32 partials
  const size_t xb_bytes   = (size_t)2048 * 64 * 256 * 2;  // 64 MB bf16 x
  unsigned short* Wb = (unsigned short*)d_ws;
  float* part = (float*)((char*)d_ws + wb_bytes);
  bool use_xb = ws_size >= wb_bytes + part_bytes + xb_bytes;
  unsigned short* xb =
      use_xb ? (unsigned short*)((char*)d_ws + wb_bytes + part_bytes) : nullptr;

  w2b_kernel<<<4096, 256, 0, stream>>>(W_ff, Wb);
  attn_kernel<<<2048, 256, 0, stream>>>(value, key, query, attn, xb);
  dim3 gb(32, 4, KS);
  if (use_xb)
    ff_kernel<true><<<gb, 256, 0, stream>>>(xb, nullptr, nullptr, Wb, part, 16384 / KS);
  else
    ff_kernel<false><<<gb, 256, 0, stream>>>(nullptr, attn, query, Wb, part, 16384 / KS);
  relu_kernel<<<2048, 256, 0, stream>>>(part, b_ff, out, KS);
}